// Round 15
// baseline (113.028 us; speedup 1.0000x reference)
//
#include <hip/hip_runtime.h>
#include <math.h>
#include <stdint.h>

#define N_NODES 50000
#define N_EDGES 800000
#define IN_FEATS 128
#define HIDDEN 64

// CSR build: 32 edge-chunks x (in|out) x 4 node-quarters, counts in LDS (packed
// 2 nodes per u32). The in-histogram pass ALSO emits each edge's slot index
// (epos, u16) so the CSR fill is a single coalesced pass. Zero global atomics
// (r6 post-mortem: device atomics write ~32B through to HBM each).
#define CSPLIT 32
#define CHUNK (N_EDGES / CSPLIT)   // 25000 edges, exact
#define NQUART (N_NODES / 4)       // 12500 nodes per quarter
#define NQWORDS (NQUART / 2)       // 6250 packed u32 (25 KB LDS)

#define NB_HIST 256                // 32 chunks x 2 kinds x 4 quarters
#define NB_E4 782                  // ceil(200000/256) edge-quad blocks
#define NB_GEMM 782                // ceil(50000/64) 64-row MFMA tiles
#define NBG 6250                   // gather blocks per feature-half plane
#define PLANE_ELEMS ((size_t)N_NODES * 32)  // bf16 elems per y-plane (3.2 MB)

typedef __attribute__((ext_vector_type(8))) short bf16x8;
typedef __attribute__((ext_vector_type(4))) float f32x4;

__device__ __forceinline__ unsigned short f2bf(float f) {
    unsigned u = __float_as_uint(f);
    u = (u + 0x7FFF + ((u >> 16) & 1)) >> 16;  // RNE
    return (unsigned short)u;
}

// scaled accumulate of a bf16x8 row (uint4) with per-edge c_src factor
#define ACC8F(A, r, cs)                                        \
    A[0] = fmaf(cs, __uint_as_float((r).x << 16), A[0]);       \
    A[1] = fmaf(cs, __uint_as_float((r).x & 0xffff0000u), A[1]); \
    A[2] = fmaf(cs, __uint_as_float((r).y << 16), A[2]);       \
    A[3] = fmaf(cs, __uint_as_float((r).y & 0xffff0000u), A[3]); \
    A[4] = fmaf(cs, __uint_as_float((r).z << 16), A[4]);       \
    A[5] = fmaf(cs, __uint_as_float((r).z & 0xffff0000u), A[5]); \
    A[6] = fmaf(cs, __uint_as_float((r).w << 16), A[6]);       \
    A[7] = fmaf(cs, __uint_as_float((r).w & 0xffff0000u), A[7]);

// --- FUSED launch 1: blocks [0, NB_HIST) = histograms (LDS atomics) ;
//     blocks [NB_HIST, +NB_GEMM) = MFMA GEMM yb = bf16(x @ W1), UNSCALED,
//     stored as two feature-half planes [plane][node][32] (64 B rows) so the
//     gather's hot table is 3.2 MB = per-XCD-L2-resident (r14 theory). ---
__global__ __launch_bounds__(256) void hist_gemm_kernel(const int* __restrict__ src,
                                                        const int* __restrict__ dst,
                                                        unsigned short* __restrict__ epos,
                                                        unsigned* __restrict__ pin,
                                                        unsigned* __restrict__ pout,
                                                        const float* __restrict__ x,
                                                        const float* __restrict__ W,
                                                        unsigned short* __restrict__ yb) {
    __shared__ union {
        unsigned cnt[NQWORDS];   // 25 KB (hist blocks)
        bf16x8 bfrag[16][64];    // 16 KB (gemm blocks)
    } u;
    if (blockIdx.x < NB_HIST) {
        int b = blockIdx.x;
        int c = b >> 3;
        int kind = (b >> 2) & 1;   // 0 = in (dst) + epos, 1 = out (src)
        int quar = b & 3;
        int lo = quar * NQUART;
        for (int i = threadIdx.x; i < NQWORDS; i += 256) u.cnt[i] = 0;
        __syncthreads();
        if (kind == 0) {
            const int4* d4 = reinterpret_cast<const int4*>(dst + c * CHUNK);
            for (int i = threadIdx.x; i < CHUNK / 4; i += 256) {
                int4 d = d4[i];
                int e = c * CHUNK + i * 4;
                unsigned q, old;
                q = (unsigned)(d.x - lo);
                if (q < NQUART) { old = atomicAdd(&u.cnt[q >> 1], 1u << ((q & 1) * 16));
                                  epos[e + 0] = (unsigned short)(old >> ((q & 1) * 16)); }
                q = (unsigned)(d.y - lo);
                if (q < NQUART) { old = atomicAdd(&u.cnt[q >> 1], 1u << ((q & 1) * 16));
                                  epos[e + 1] = (unsigned short)(old >> ((q & 1) * 16)); }
                q = (unsigned)(d.z - lo);
                if (q < NQUART) { old = atomicAdd(&u.cnt[q >> 1], 1u << ((q & 1) * 16));
                                  epos[e + 2] = (unsigned short)(old >> ((q & 1) * 16)); }
                q = (unsigned)(d.w - lo);
                if (q < NQUART) { old = atomicAdd(&u.cnt[q >> 1], 1u << ((q & 1) * 16));
                                  epos[e + 3] = (unsigned short)(old >> ((q & 1) * 16)); }
            }
        } else {
            const int4* s4 = reinterpret_cast<const int4*>(src + c * CHUNK);
            for (int i = threadIdx.x; i < CHUNK / 4; i += 256) {
                int4 s = s4[i];
                unsigned q;
                q = (unsigned)(s.x - lo); if (q < NQUART) atomicAdd(&u.cnt[q >> 1], 1u << ((q & 1) * 16));
                q = (unsigned)(s.y - lo); if (q < NQUART) atomicAdd(&u.cnt[q >> 1], 1u << ((q & 1) * 16));
                q = (unsigned)(s.z - lo); if (q < NQUART) atomicAdd(&u.cnt[q >> 1], 1u << ((q & 1) * 16));
                q = (unsigned)(s.w - lo); if (q < NQUART) atomicAdd(&u.cnt[q >> 1], 1u << ((q & 1) * 16));
            }
        }
        __syncthreads();
        unsigned* outp = (kind ? pout : pin) + c * (N_NODES / 2) + quar * NQWORDS;
        for (int i = threadIdx.x; i < NQWORDS; i += 256) outp[i] = u.cnt[i];
        return;
    }
    // ---- MFMA GEMM: yb = bf16(x @ W1), unscaled, plane-split store ----
    // C layout (m89): col = lane&15, row = (lane>>4)*4 + reg.
    int gb = blockIdx.x - NB_HIST;
    for (int idx = threadIdx.x; idx < 16 * 64; idx += 256) {
        int f = idx >> 6, l = idx & 63;
        int nt = f >> 2, kt = f & 3;
        int col = nt * 16 + (l & 15);
        int k0 = kt * 32 + (l >> 4) * 8;
        bf16x8 bv;
#pragma unroll
        for (int j = 0; j < 8; ++j) bv[j] = (short)f2bf(W[(k0 + j) * HIDDEN + col]);
        u.bfrag[f][l] = bv;
    }
    __syncthreads();
    int wid = threadIdx.x >> 6, l = threadIdx.x & 63;
    bf16x8 Breg[16];
#pragma unroll
    for (int f = 0; f < 16; ++f) Breg[f] = u.bfrag[f][l];

    int row0 = gb * 64 + wid * 16;  // this wave's 16-row tile
    int arow = row0 + (l & 15);
    int asafe = min(arow, N_NODES - 1);  // clamp OOB rows (stores guarded)
    const float* xr = x + (size_t)asafe * IN_FEATS + (l >> 4) * 8;
    f32x4 acc0 = {0.f, 0.f, 0.f, 0.f};
    f32x4 acc1 = {0.f, 0.f, 0.f, 0.f};
    f32x4 acc2 = {0.f, 0.f, 0.f, 0.f};
    f32x4 acc3 = {0.f, 0.f, 0.f, 0.f};
#pragma unroll
    for (int kt = 0; kt < 4; ++kt) {
        float4 a0 = *reinterpret_cast<const float4*>(xr + kt * 32);
        float4 a1 = *reinterpret_cast<const float4*>(xr + kt * 32 + 4);
        bf16x8 av;
        av[0] = (short)f2bf(a0.x); av[1] = (short)f2bf(a0.y);
        av[2] = (short)f2bf(a0.z); av[3] = (short)f2bf(a0.w);
        av[4] = (short)f2bf(a1.x); av[5] = (short)f2bf(a1.y);
        av[6] = (short)f2bf(a1.z); av[7] = (short)f2bf(a1.w);
        acc0 = __builtin_amdgcn_mfma_f32_16x16x32_bf16(av, Breg[0 * 4 + kt], acc0, 0, 0, 0);
        acc1 = __builtin_amdgcn_mfma_f32_16x16x32_bf16(av, Breg[1 * 4 + kt], acc1, 0, 0, 0);
        acc2 = __builtin_amdgcn_mfma_f32_16x16x32_bf16(av, Breg[2 * 4 + kt], acc2, 0, 0, 0);
        acc3 = __builtin_amdgcn_mfma_f32_16x16x32_bf16(av, Breg[3 * 4 + kt], acc3, 0, 0, 0);
    }
#pragma unroll
    for (int i = 0; i < 4; ++i) {
        int row = row0 + (l >> 4) * 4 + i;
        if (row < N_NODES) {
            // cols 0-31 -> plane 0 ; cols 32-63 -> plane 1 (32-elem rows)
            unsigned short* y0 = yb + (size_t)row * 32 + (l & 15);
            unsigned short* y1 = y0 + PLANE_ELEMS;
            y0[0]  = f2bf(acc0[i]);
            y0[16] = f2bf(acc1[i]);
            y1[0]  = f2bf(acc2[i]);
            y1[16] = f2bf(acc3[i]);
        }
    }
}

// --- fused: degree-sum + c_src/c_dst + per-block exclusive scan (blocks 0..48,
//     1024 nodes each, 4/thread) ; block 49 = w2prep (w2s=W2@Ws, w2d=W2@Wd) ---
__global__ __launch_bounds__(256) void prep_kernel(const unsigned* __restrict__ pin,
                                                   const unsigned* __restrict__ pout,
                                                   float* __restrict__ cs,
                                                   float* __restrict__ cd,
                                                   int* __restrict__ offs,
                                                   int* __restrict__ bsum,
                                                   const float* __restrict__ W2,
                                                   const float* __restrict__ We,
                                                   const float* __restrict__ b2,
                                                   float* __restrict__ w2s,
                                                   float* __restrict__ w2d,
                                                   float* __restrict__ w2c) {
    int b = blockIdx.x;
    int t = threadIdx.x;
    if (b == 49) {  // w2prep tail block (no barriers on this path)
        if (t < 64) {
            float s = 0.f, d = 0.f;
            for (int j = 0; j < HIDDEN; ++j) {
                float w = W2[t * HIDDEN + j];
                s = fmaf(w, We[j], s);
                d = fmaf(w, We[HIDDEN + j], d);
            }
            w2s[t] = s;
            w2d[t] = d;
        } else if (t == 64) {
            float s = 0.f, d = 0.f;
            for (int j = 0; j < HIDDEN; ++j) {
                s = fmaf(We[j], b2[j], s);
                d = fmaf(We[HIDDEN + j], b2[j], d);
            }
            w2c[0] = s;
            w2c[1] = d;
        }
        return;
    }
    __shared__ int sums[256];
    int v0 = b * 1024 + t * 4;
    bool ok = v0 < N_NODES;
    unsigned si0 = 0, si1 = 0, si2 = 0, si3 = 0;
    unsigned so0 = 0, so1 = 0, so2 = 0, so3 = 0;
    if (ok) {
        int w0 = v0 >> 1;  // even (v0 % 4 == 0) -> uint2 aligned
#pragma unroll
        for (int c = 0; c < CSPLIT; ++c) {
            uint2 a = *reinterpret_cast<const uint2*>(pin + (size_t)c * (N_NODES / 2) + w0);
            uint2 o = *reinterpret_cast<const uint2*>(pout + (size_t)c * (N_NODES / 2) + w0);
            si0 += a.x & 0xffffu; si1 += a.x >> 16;
            si2 += a.y & 0xffffu; si3 += a.y >> 16;
            so0 += o.x & 0xffffu; so1 += o.x >> 16;
            so2 += o.y & 0xffffu; so3 += o.y >> 16;
        }
        *reinterpret_cast<float4*>(cs + v0) =
            make_float4(rsqrtf(fmaxf((float)so0, 1.f)), rsqrtf(fmaxf((float)so1, 1.f)),
                        rsqrtf(fmaxf((float)so2, 1.f)), rsqrtf(fmaxf((float)so3, 1.f)));
        *reinterpret_cast<float4*>(cd + v0) =
            make_float4(rsqrtf(fmaxf((float)si0, 1.f)), rsqrtf(fmaxf((float)si1, 1.f)),
                        rsqrtf(fmaxf((float)si2, 1.f)), rsqrtf(fmaxf((float)si3, 1.f)));
    }
    int d0 = (int)si0, d1 = (int)si1, d2 = (int)si2, d3 = (int)si3;
    sums[t] = d0 + d1 + d2 + d3;
    __syncthreads();
    for (int o = 1; o < 256; o <<= 1) {
        int v = (t >= o) ? sums[t - o] : 0;
        __syncthreads();
        sums[t] += v;
        __syncthreads();
    }
    int excl = (t == 0) ? 0 : sums[t - 1];
    if (ok) {
        *reinterpret_cast<int4*>(offs + v0) =
            make_int4(excl, excl + d0, excl + d0 + d1, excl + d0 + d1 + d2);
    }
    if (t == 255) bsum[b] = sums[255];
}

// --- finalize offs + RELATIVE per-chunk base offsets (u16) ---
__global__ __launch_bounds__(256) void scan3_base_kernel(int* __restrict__ offs,
                                                         const int* __restrict__ bsum,
                                                         const unsigned* __restrict__ pin,
                                                         unsigned short* __restrict__ baser) {
    __shared__ int sbase[64];
    int t = threadIdx.x;
    if (t < 64) {
        int val = (t < 49) ? bsum[t] : 0;
        int s = val;
#pragma unroll
        for (int o = 1; o < 64; o <<= 1) {
            int u = __shfl_up(s, o, 64);
            if (t >= o) s += u;
        }
        sbase[t] = s - val;  // exclusive
    }
    __syncthreads();
    int v = blockIdx.x * 256 + t;
    if (v >= N_NODES) return;
    int off = offs[v] + sbase[v >> 10];
    offs[v] = off;
    int rel = 0;
    int sh = (v & 1) * 16;
#pragma unroll
    for (int c = 0; c < CSPLIT; ++c) {
        baser[(size_t)c * N_NODES + v] = (unsigned short)rel;
        rel += (int)((pin[(size_t)c * (N_NODES / 2) + (v >> 1)] >> sh) & 0xffffu);
    }
    if (v == 0) offs[N_NODES] = N_EDGES;
}

// --- CSR fill: slot = offs[dst] + baser[c][dst] + epos ---
__global__ __launch_bounds__(256) void fill_kernel(const int* __restrict__ src,
                                                   const int* __restrict__ dst,
                                                   const unsigned short* __restrict__ epos,
                                                   const int* __restrict__ offs,
                                                   const unsigned short* __restrict__ baser,
                                                   int* __restrict__ csr_src) {
    int t = blockIdx.x * 256 + threadIdx.x;
    int e0 = t * 4;
    if (e0 >= N_EDGES) return;
    int c = e0 / CHUNK;  // CHUNK % 4 == 0 -> uniform over the 4 edges
    const unsigned short* brc = baser + (size_t)c * N_NODES;
    int4 s = *reinterpret_cast<const int4*>(src + e0);
    int4 d = *reinterpret_cast<const int4*>(dst + e0);
    ushort4 ep = *reinterpret_cast<const ushort4*>(epos + e0);
    csr_src[offs[d.x] + brc[d.x] + ep.x] = s.x;
    csr_src[offs[d.y] + brc[d.y] + ep.y] = s.y;
    csr_src[offs[d.z] + brc[d.z] + ep.z] = s.z;
    csr_src[offs[d.w] + brc[d.w] + ep.w] = s.w;
}

// --- layer1 gather over ONE 3.2MB feature-half plane (per-XCD-L2-resident);
//     plane-major grid: blocks [0,NBG) = plane 0, [NBG,2*NBG) = plane 1.
//     16 edge-slots x 4 lanes x uint4 (64 B rows); TWO nodes per wave.
//     relu/bias + layer-2 partial dot -> t[2v+plane] (float2). ---
__global__ __launch_bounds__(256) void gather_t_kernel(const unsigned short* __restrict__ y,
                                                       const int* __restrict__ offs,
                                                       const int* __restrict__ csr_src,
                                                       const float* __restrict__ c_src,
                                                       const float* __restrict__ c_dst,
                                                       const float* __restrict__ b1,
                                                       const float* __restrict__ w2s,
                                                       const float* __restrict__ w2d,
                                                       float2* __restrict__ t) {
    int plane = (blockIdx.x >= NBG) ? 1 : 0;
    int bb = blockIdx.x - plane * NBG;
    const unsigned short* yp = y + (size_t)plane * PLANE_ELEMS;
    int wid = threadIdx.x >> 6, l = threadIdx.x & 63;
    int slot = l >> 2, q4 = l & 3;  // 16 edge-slots x 4 feature-octets
    int v0 = bb * 8 + wid * 2;      // 6250 * 8 = 50000 exact
    int v1 = v0 + 1;
    int beg0 = offs[v0], end0 = offs[v0 + 1], end1 = offs[v0 + 2];
    int k0 = beg0, k1 = end0;  // v1's edges start where v0's end
    float acc0[8] = {0.f, 0.f, 0.f, 0.f, 0.f, 0.f, 0.f, 0.f};
    float acc1[8] = {0.f, 0.f, 0.f, 0.f, 0.f, 0.f, 0.f, 0.f};
    // dual main loop: 2 independent 16-edge gather batches in flight
    while (k0 + 16 <= end0 && k1 + 16 <= end1) {
        int sA = csr_src[k0 + slot];
        int sB = csr_src[k1 + slot];
        float csA = c_src[sA];
        float csB = c_src[sB];
        uint4 rA = *reinterpret_cast<const uint4*>(yp + (size_t)sA * 32 + q4 * 8);
        uint4 rB = *reinterpret_cast<const uint4*>(yp + (size_t)sB * 32 + q4 * 8);
        ACC8F(acc0, rA, csA);
        ACC8F(acc1, rB, csB);
        k0 += 16;
        k1 += 16;
    }
    while (k0 + 16 <= end0) {
        int s = csr_src[k0 + slot];
        float cs = c_src[s];
        uint4 r = *reinterpret_cast<const uint4*>(yp + (size_t)s * 32 + q4 * 8);
        ACC8F(acc0, r, cs);
        k0 += 16;
    }
    while (k1 + 16 <= end1) {
        int s = csr_src[k1 + slot];
        float cs = c_src[s];
        uint4 r = *reinterpret_cast<const uint4*>(yp + (size_t)s * 32 + q4 * 8);
        ACC8F(acc1, r, cs);
        k1 += 16;
    }
    if (slot < end0 - k0) {
        int s = csr_src[k0 + slot];
        float cs = c_src[s];
        uint4 r = *reinterpret_cast<const uint4*>(yp + (size_t)s * 32 + q4 * 8);
        ACC8F(acc0, r, cs);
    }
    if (slot < end1 - k1) {
        int s = csr_src[k1 + slot];
        float cs = c_src[s];
        uint4 r = *reinterpret_cast<const uint4*>(yp + (size_t)s * 32 + q4 * 8);
        ACC8F(acc1, r, cs);
    }
    // combine 16 slots (lanes with equal q4), both nodes
#pragma unroll
    for (int i = 0; i < 8; ++i) {
        acc0[i] += __shfl_xor(acc0[i], 4, 64);
        acc0[i] += __shfl_xor(acc0[i], 8, 64);
        acc0[i] += __shfl_xor(acc0[i], 16, 64);
        acc0[i] += __shfl_xor(acc0[i], 32, 64);
        acc1[i] += __shfl_xor(acc1[i], 4, 64);
        acc1[i] += __shfl_xor(acc1[i], 8, 64);
        acc1[i] += __shfl_xor(acc1[i], 16, 64);
        acc1[i] += __shfl_xor(acc1[i], 32, 64);
    }
    // epilogue on features [plane*32 + q4*8, +8)
    int fb = plane * 32 + q4 * 8;
    float4 ba = *reinterpret_cast<const float4*>(b1 + fb);
    float4 bb4 = *reinterpret_cast<const float4*>(b1 + fb + 4);
    float4 wsa = *reinterpret_cast<const float4*>(w2s + fb);
    float4 wsb = *reinterpret_cast<const float4*>(w2s + fb + 4);
    float4 wda = *reinterpret_cast<const float4*>(w2d + fb);
    float4 wdb = *reinterpret_cast<const float4*>(w2d + fb + 4);
    float c0 = c_dst[v0], c1 = c_dst[v1];
    float h0, h1, h2, h3, h4, h5, h6, h7;
    h0 = fmaxf(fmaf(c0, acc0[0], ba.x), 0.f);
    h1 = fmaxf(fmaf(c0, acc0[1], ba.y), 0.f);
    h2 = fmaxf(fmaf(c0, acc0[2], ba.z), 0.f);
    h3 = fmaxf(fmaf(c0, acc0[3], ba.w), 0.f);
    h4 = fmaxf(fmaf(c0, acc0[4], bb4.x), 0.f);
    h5 = fmaxf(fmaf(c0, acc0[5], bb4.y), 0.f);
    h6 = fmaxf(fmaf(c0, acc0[6], bb4.z), 0.f);
    h7 = fmaxf(fmaf(c0, acc0[7], bb4.w), 0.f);
    float ps0 = h0 * wsa.x + h1 * wsa.y + h2 * wsa.z + h3 * wsa.w
              + h4 * wsb.x + h5 * wsb.y + h6 * wsb.z + h7 * wsb.w;
    float pd0 = h0 * wda.x + h1 * wda.y + h2 * wda.z + h3 * wda.w
              + h4 * wdb.x + h5 * wdb.y + h6 * wdb.z + h7 * wdb.w;
    h0 = fmaxf(fmaf(c1, acc1[0], ba.x), 0.f);
    h1 = fmaxf(fmaf(c1, acc1[1], ba.y), 0.f);
    h2 = fmaxf(fmaf(c1, acc1[2], ba.z), 0.f);
    h3 = fmaxf(fmaf(c1, acc1[3], ba.w), 0.f);
    h4 = fmaxf(fmaf(c1, acc1[4], bb4.x), 0.f);
    h5 = fmaxf(fmaf(c1, acc1[5], bb4.y), 0.f);
    h6 = fmaxf(fmaf(c1, acc1[6], bb4.z), 0.f);
    h7 = fmaxf(fmaf(c1, acc1[7], bb4.w), 0.f);
    float ps1 = h0 * wsa.x + h1 * wsa.y + h2 * wsa.z + h3 * wsa.w
              + h4 * wsb.x + h5 * wsb.y + h6 * wsb.z + h7 * wsb.w;
    float pd1 = h0 * wda.x + h1 * wda.y + h2 * wda.z + h3 * wda.w
              + h4 * wdb.x + h5 * wdb.y + h6 * wdb.z + h7 * wdb.w;
    // reduce across the 4 q4 groups -> every lane holds the full half-dot
#pragma unroll
    for (int o = 1; o <= 2; o <<= 1) {
        ps0 += __shfl_xor(ps0, o, 64);
        pd0 += __shfl_xor(pd0, o, 64);
        ps1 += __shfl_xor(ps1, o, 64);
        pd1 += __shfl_xor(pd1, o, 64);
    }
    if (l == 0) {
        float cs0 = c_src[v0];
        t[2 * v0 + plane] = make_float2(cs0 * ps0, cs0 * pd0);
    } else if (l == 1) {
        float cs1 = c_src[v1];
        t[2 * v1 + plane] = make_float2(cs1 * ps1, cs1 * pd1);
    }
}

// --- layer2 scalar gather: a_s[v] = c_dst[v]*sum(t over in-edges) + Ws.b2 ;
//     t[2s] + t[2s+1] are the two plane-halves -> one float4 load per edge ---
__global__ __launch_bounds__(256) void gather2_kernel(const float2* __restrict__ t,
                                                      const int* __restrict__ offs,
                                                      const int* __restrict__ csr_src,
                                                      const float* __restrict__ c_dst,
                                                      const float* __restrict__ w2c,
                                                      float* __restrict__ a_s,
                                                      float* __restrict__ a_d) {
    int wid = threadIdx.x >> 6, l = threadIdx.x & 63;
    int sub = l >> 4, q = l & 15;
    int v = blockIdx.x * 16 + wid * 4 + sub;  // grid exact: 3125 * 16 = 50000
    int beg = offs[v], end = offs[v + 1];
    float ps = 0.f, pd = 0.f;
    for (int k = beg + q; k < end; k += 16) {
        int s = csr_src[k];
        float4 tt = *reinterpret_cast<const float4*>(t + 2 * (size_t)s);
        ps += tt.x + tt.z;
        pd += tt.y + tt.w;
    }
#pragma unroll
    for (int o = 1; o <= 8; o <<= 1) {
        ps += __shfl_xor(ps, o, 64);
        pd += __shfl_xor(pd, o, 64);
    }
    if (q == 0) {
        float c = c_dst[v];
        a_s[v] = fmaf(c, ps, w2c[0]);
        a_d[v] = fmaf(c, pd, w2c[1]);
    }
}

// --- out[e] = sigmoid(a_s[src] + a_d[dst] + efeat.Wf + be), 8 edges/thread ---
__global__ __launch_bounds__(256) void edge_out_kernel(const int* __restrict__ src,
                                                       const int* __restrict__ dst,
                                                       const float* __restrict__ efeat,
                                                       const float* __restrict__ We,
                                                       const float* __restrict__ be,
                                                       const float* __restrict__ a_s,
                                                       const float* __restrict__ a_d,
                                                       float* __restrict__ out) {
    int t = blockIdx.x * 256 + threadIdx.x;
    int e0 = t * 8;
    if (e0 >= N_EDGES) return;  // N_EDGES % 8 == 0 -> full octets
    float w0 = We[2 * HIDDEN + 0], w1 = We[2 * HIDDEN + 1], w2 = We[2 * HIDDEN + 2];
    float b = be[0];
    int4 sA = *reinterpret_cast<const int4*>(src + e0);
    int4 sB = *reinterpret_cast<const int4*>(src + e0 + 4);
    int4 dA = *reinterpret_cast<const int4*>(dst + e0);
    int4 dB = *reinterpret_cast<const int4*>(dst + e0 + 4);
    const float4* f = reinterpret_cast<const float4*>(efeat + (long)e0 * 3);
    float4 f0 = f[0], f1 = f[1], f2 = f[2], f3 = f[3], f4 = f[4], f5 = f[5];
    float as0 = a_s[sA.x], as1 = a_s[sA.y], as2 = a_s[sA.z], as3 = a_s[sA.w];
    float as4 = a_s[sB.x], as5 = a_s[sB.y], as6 = a_s[sB.z], as7 = a_s[sB.w];
    float ad0 = a_d[dA.x], ad1 = a_d[dA.y], ad2 = a_d[dA.z], ad3 = a_d[dA.w];
    float ad4 = a_d[dB.x], ad5 = a_d[dB.y], ad6 = a_d[dB.z], ad7 = a_d[dB.w];
    float4 oA, oB;
    float z;
    z = as0 + ad0 + f0.x * w0 + f0.y * w1 + f0.z * w2 + b;
    oA.x = 1.0f / (1.0f + __expf(-z));
    z = as1 + ad1 + f0.w * w0 + f1.x * w1 + f1.y * w2 + b;
    oA.y = 1.0f / (1.0f + __expf(-z));
    z = as2 + ad2 + f1.z * w0 + f1.w * w1 + f2.x * w2 + b;
    oA.z = 1.0f / (1.0f + __expf(-z));
    z = as3 + ad3 + f2.y * w0 + f2.z * w1 + f2.w * w2 + b;
    oA.w = 1.0f / (1.0f + __expf(-z));
    z = as4 + ad4 + f3.x * w0 + f3.y * w1 + f3.z * w2 + b;
    oB.x = 1.0f / (1.0f + __expf(-z));
    z = as5 + ad5 + f3.w * w0 + f4.x * w1 + f4.y * w2 + b;
    oB.y = 1.0f / (1.0f + __expf(-z));
    z = as6 + ad6 + f4.z * w0 + f4.w * w1 + f5.x * w2 + b;
    oB.z = 1.0f / (1.0f + __expf(-z));
    z = as7 + ad7 + f5.y * w0 + f5.z * w1 + f5.w * w2 + b;
    oB.w = 1.0f / (1.0f + __expf(-z));
    *reinterpret_cast<float4*>(out + e0) = oA;
    *reinterpret_cast<float4*>(out + e0 + 4) = oB;
}

extern "C" void kernel_launch(void* const* d_in, const int* in_sizes, int n_in,
                              void* d_out, int out_size, void* d_ws, size_t ws_size,
                              hipStream_t stream) {
    const float* x     = (const float*)d_in[0];
    const float* efeat = (const float*)d_in[1];
    const int*   src   = (const int*)d_in[2];
    const int*   dst   = (const int*)d_in[3];
    const float* W1    = (const float*)d_in[4];
    const float* b1    = (const float*)d_in[5];
    const float* W2    = (const float*)d_in[6];
    const float* b2    = (const float*)d_in[7];
    const float* We    = (const float*)d_in[8];
    const float* be    = (const float*)d_in[9];
    float* out = (float*)d_out;

    // 256B-aligned workspace carve-up; ~23 MB total.
    char* p = (char*)d_ws;
    auto alloc = [&](size_t bytes) {
        char* r = p;
        p += (bytes + 255) & ~(size_t)255;
        return r;
    };
    float* c_src   = (float*)alloc((size_t)N_NODES * 4);
    float* c_dst   = (float*)alloc((size_t)N_NODES * 4);
    float* a_s     = (float*)alloc((size_t)N_NODES * 4);
    float* a_d     = (float*)alloc((size_t)N_NODES * 4);
    int*   offs    = (int*)alloc((size_t)(N_NODES + 1) * 4);
    int*   bsum    = (int*)alloc(64 * 4);
    float* w2s     = (float*)alloc(HIDDEN * 4);
    float* w2d     = (float*)alloc(HIDDEN * 4);
    float* w2c     = (float*)alloc(2 * 4);
    unsigned*       pin   = (unsigned*)alloc((size_t)CSPLIT * (N_NODES / 2) * 4);  // 3.2 MB
    unsigned*       pout  = (unsigned*)alloc((size_t)CSPLIT * (N_NODES / 2) * 4);  // 3.2 MB
    unsigned short* epos  = (unsigned short*)alloc((size_t)N_EDGES * 2);           // 1.6 MB
    unsigned short* baser = (unsigned short*)alloc((size_t)CSPLIT * N_NODES * 2);  // 3.2 MB
    int*            csr_src = (int*)alloc((size_t)N_EDGES * 4);                    // 3.2 MB
    unsigned short* yb    = (unsigned short*)alloc((size_t)2 * PLANE_ELEMS * 2);   // 6.4 MB
    float2*         t     = (float2*)alloc((size_t)2 * N_NODES * 8);               // 800 KB

    const int NB_V = (N_NODES + 255) / 256;  // 196

    // launch 1: histograms (LDS atomics) overlapped with dep-free MFMA GEMM
    hist_gemm_kernel<<<NB_HIST + NB_GEMM, 256, 0, stream>>>(src, dst, epos, pin, pout,
                                                            x, W1, yb);
    // degree/scan/w2 prep ; offs + relative base finalize
    prep_kernel<<<50, 256, 0, stream>>>(pin, pout, c_src, c_dst, offs, bsum,
                                        W2, We, b2, w2s, w2d, w2c);
    scan3_base_kernel<<<NB_V, 256, 0, stream>>>(offs, bsum, pin, baser);
    // CSR fill
    fill_kernel<<<NB_E4, 256, 0, stream>>>(src, dst, epos, offs, baser, csr_src);
    // fused gather1 + relu + layer-2 partial dots -> t (plane-major, L2-resident)
    gather_t_kernel<<<2 * NBG, 256, 0, stream>>>(yb, offs, csr_src, c_src, c_dst,
                                                 b1, w2s, w2d, t);
    // layer-2 scalar gather -> a_s, a_d
    gather2_kernel<<<N_NODES / 16, 256, 0, stream>>>(t, offs, csr_src, c_dst, w2c, a_s, a_d);
    // edge output
    edge_out_kernel<<<(N_EDGES / 8 + 255) / 256, 256, 0, stream>>>(src, dst, efeat, We, be,
                                                                   a_s, a_d, out);
}

// Round 16
// 99.082 us; speedup vs baseline: 1.1408x; 1.1408x over previous
//
#include <hip/hip_runtime.h>
#include <math.h>
#include <stdint.h>

#define N_NODES 50000
#define N_EDGES 800000
#define IN_FEATS 128
#define HIDDEN 64

// CSR build: 32 edge-chunks x (in|out) x 4 node-quarters, counts in LDS (packed
// 2 nodes per u32). The in-histogram pass ALSO emits each edge's slot index
// (epos, u16) so the CSR fill is a single coalesced pass. Zero global atomics
// (r6 post-mortem: device atomics write ~32B through to HBM each).
#define CSPLIT 32
#define CHUNK (N_EDGES / CSPLIT)   // 25000 edges, exact
#define NQUART (N_NODES / 4)       // 12500 nodes per quarter
#define NQWORDS (NQUART / 2)       // 6250 packed u32 (25 KB LDS)

#define NB_HIST 256                // 32 chunks x 2 kinds x 4 quarters
#define NB_E4 782                  // ceil(200000/256) edge-quad blocks
#define NB_GEMM 782                // ceil(50000/64) 64-row MFMA tiles

typedef __attribute__((ext_vector_type(8))) short bf16x8;
typedef __attribute__((ext_vector_type(4))) float f32x4;

__device__ __forceinline__ unsigned short f2bf(float f) {
    unsigned u = __float_as_uint(f);
    u = (u + 0x7FFF + ((u >> 16) & 1)) >> 16;  // RNE
    return (unsigned short)u;
}

// scaled accumulate of a bf16x8 row (uint4) with per-edge c_src factor
#define ACC8F(A, r, cs)                                        \
    A[0] = fmaf(cs, __uint_as_float((r).x << 16), A[0]);       \
    A[1] = fmaf(cs, __uint_as_float((r).x & 0xffff0000u), A[1]); \
    A[2] = fmaf(cs, __uint_as_float((r).y << 16), A[2]);       \
    A[3] = fmaf(cs, __uint_as_float((r).y & 0xffff0000u), A[3]); \
    A[4] = fmaf(cs, __uint_as_float((r).z << 16), A[4]);       \
    A[5] = fmaf(cs, __uint_as_float((r).z & 0xffff0000u), A[5]); \
    A[6] = fmaf(cs, __uint_as_float((r).w << 16), A[6]);       \
    A[7] = fmaf(cs, __uint_as_float((r).w & 0xffff0000u), A[7]);

// --- FUSED launch 1: blocks [0, NB_HIST) = histograms (LDS atomics) ;
//     blocks [NB_HIST, +NB_GEMM) = MFMA GEMM yb = bf16(x @ W1), UNSCALED
//     (c_src applied at gather time -- gemm has no deps, hides under hist). ---
__global__ __launch_bounds__(256) void hist_gemm_kernel(const int* __restrict__ src,
                                                        const int* __restrict__ dst,
                                                        unsigned short* __restrict__ epos,
                                                        unsigned* __restrict__ pin,
                                                        unsigned* __restrict__ pout,
                                                        const float* __restrict__ x,
                                                        const float* __restrict__ W,
                                                        unsigned short* __restrict__ yb) {
    __shared__ union {
        unsigned cnt[NQWORDS];   // 25 KB (hist blocks)
        bf16x8 bfrag[16][64];    // 16 KB (gemm blocks)
    } u;
    if (blockIdx.x < NB_HIST) {
        int b = blockIdx.x;
        int c = b >> 3;
        int kind = (b >> 2) & 1;   // 0 = in (dst) + epos, 1 = out (src)
        int quar = b & 3;
        int lo = quar * NQUART;
        for (int i = threadIdx.x; i < NQWORDS; i += 256) u.cnt[i] = 0;
        __syncthreads();
        if (kind == 0) {
            const int4* d4 = reinterpret_cast<const int4*>(dst + c * CHUNK);
            for (int i = threadIdx.x; i < CHUNK / 4; i += 256) {
                int4 d = d4[i];
                int e = c * CHUNK + i * 4;
                unsigned q, old;
                q = (unsigned)(d.x - lo);
                if (q < NQUART) { old = atomicAdd(&u.cnt[q >> 1], 1u << ((q & 1) * 16));
                                  epos[e + 0] = (unsigned short)(old >> ((q & 1) * 16)); }
                q = (unsigned)(d.y - lo);
                if (q < NQUART) { old = atomicAdd(&u.cnt[q >> 1], 1u << ((q & 1) * 16));
                                  epos[e + 1] = (unsigned short)(old >> ((q & 1) * 16)); }
                q = (unsigned)(d.z - lo);
                if (q < NQUART) { old = atomicAdd(&u.cnt[q >> 1], 1u << ((q & 1) * 16));
                                  epos[e + 2] = (unsigned short)(old >> ((q & 1) * 16)); }
                q = (unsigned)(d.w - lo);
                if (q < NQUART) { old = atomicAdd(&u.cnt[q >> 1], 1u << ((q & 1) * 16));
                                  epos[e + 3] = (unsigned short)(old >> ((q & 1) * 16)); }
            }
        } else {
            const int4* s4 = reinterpret_cast<const int4*>(src + c * CHUNK);
            for (int i = threadIdx.x; i < CHUNK / 4; i += 256) {
                int4 s = s4[i];
                unsigned q;
                q = (unsigned)(s.x - lo); if (q < NQUART) atomicAdd(&u.cnt[q >> 1], 1u << ((q & 1) * 16));
                q = (unsigned)(s.y - lo); if (q < NQUART) atomicAdd(&u.cnt[q >> 1], 1u << ((q & 1) * 16));
                q = (unsigned)(s.z - lo); if (q < NQUART) atomicAdd(&u.cnt[q >> 1], 1u << ((q & 1) * 16));
                q = (unsigned)(s.w - lo); if (q < NQUART) atomicAdd(&u.cnt[q >> 1], 1u << ((q & 1) * 16));
            }
        }
        __syncthreads();
        unsigned* outp = (kind ? pout : pin) + c * (N_NODES / 2) + quar * NQWORDS;
        for (int i = threadIdx.x; i < NQWORDS; i += 256) outp[i] = u.cnt[i];
        return;
    }
    // ---- MFMA GEMM: yb = bf16(x @ W1), unscaled ----
    // C layout (m89): col = lane&15, row = (lane>>4)*4 + reg.
    int gb = blockIdx.x - NB_HIST;
    for (int idx = threadIdx.x; idx < 16 * 64; idx += 256) {
        int f = idx >> 6, l = idx & 63;
        int nt = f >> 2, kt = f & 3;
        int col = nt * 16 + (l & 15);
        int k0 = kt * 32 + (l >> 4) * 8;
        bf16x8 bv;
#pragma unroll
        for (int j = 0; j < 8; ++j) bv[j] = (short)f2bf(W[(k0 + j) * HIDDEN + col]);
        u.bfrag[f][l] = bv;
    }
    __syncthreads();
    int wid = threadIdx.x >> 6, l = threadIdx.x & 63;
    bf16x8 Breg[16];
#pragma unroll
    for (int f = 0; f < 16; ++f) Breg[f] = u.bfrag[f][l];

    int row0 = gb * 64 + wid * 16;  // this wave's 16-row tile
    int arow = row0 + (l & 15);
    int asafe = min(arow, N_NODES - 1);  // clamp OOB rows (stores guarded)
    const float* xr = x + (size_t)asafe * IN_FEATS + (l >> 4) * 8;
    f32x4 acc0 = {0.f, 0.f, 0.f, 0.f};
    f32x4 acc1 = {0.f, 0.f, 0.f, 0.f};
    f32x4 acc2 = {0.f, 0.f, 0.f, 0.f};
    f32x4 acc3 = {0.f, 0.f, 0.f, 0.f};
#pragma unroll
    for (int kt = 0; kt < 4; ++kt) {
        float4 a0 = *reinterpret_cast<const float4*>(xr + kt * 32);
        float4 a1 = *reinterpret_cast<const float4*>(xr + kt * 32 + 4);
        bf16x8 av;
        av[0] = (short)f2bf(a0.x); av[1] = (short)f2bf(a0.y);
        av[2] = (short)f2bf(a0.z); av[3] = (short)f2bf(a0.w);
        av[4] = (short)f2bf(a1.x); av[5] = (short)f2bf(a1.y);
        av[6] = (short)f2bf(a1.z); av[7] = (short)f2bf(a1.w);
        acc0 = __builtin_amdgcn_mfma_f32_16x16x32_bf16(av, Breg[0 * 4 + kt], acc0, 0, 0, 0);
        acc1 = __builtin_amdgcn_mfma_f32_16x16x32_bf16(av, Breg[1 * 4 + kt], acc1, 0, 0, 0);
        acc2 = __builtin_amdgcn_mfma_f32_16x16x32_bf16(av, Breg[2 * 4 + kt], acc2, 0, 0, 0);
        acc3 = __builtin_amdgcn_mfma_f32_16x16x32_bf16(av, Breg[3 * 4 + kt], acc3, 0, 0, 0);
    }
#pragma unroll
    for (int i = 0; i < 4; ++i) {
        int row = row0 + (l >> 4) * 4 + i;
        if (row < N_NODES) {
            unsigned short* yr = yb + (size_t)row * HIDDEN + (l & 15);
            yr[0]  = f2bf(acc0[i]);
            yr[16] = f2bf(acc1[i]);
            yr[32] = f2bf(acc2[i]);
            yr[48] = f2bf(acc3[i]);
        }
    }
}

// --- fused: degree-sum + c_src/c_dst + per-block exclusive scan (blocks 0..48,
//     1024 nodes each, 4/thread) ; block 49 = w2prep (w2s=W2@Ws, w2d=W2@Wd) ---
__global__ __launch_bounds__(256) void prep_kernel(const unsigned* __restrict__ pin,
                                                   const unsigned* __restrict__ pout,
                                                   float* __restrict__ cs,
                                                   float* __restrict__ cd,
                                                   int* __restrict__ offs,
                                                   int* __restrict__ bsum,
                                                   const float* __restrict__ W2,
                                                   const float* __restrict__ We,
                                                   const float* __restrict__ b2,
                                                   float* __restrict__ w2s,
                                                   float* __restrict__ w2d,
                                                   float* __restrict__ w2c) {
    int b = blockIdx.x;
    int t = threadIdx.x;
    if (b == 49) {  // w2prep tail block (no barriers on this path)
        if (t < 64) {
            float s = 0.f, d = 0.f;
            for (int j = 0; j < HIDDEN; ++j) {
                float w = W2[t * HIDDEN + j];
                s = fmaf(w, We[j], s);
                d = fmaf(w, We[HIDDEN + j], d);
            }
            w2s[t] = s;
            w2d[t] = d;
        } else if (t == 64) {
            float s = 0.f, d = 0.f;
            for (int j = 0; j < HIDDEN; ++j) {
                s = fmaf(We[j], b2[j], s);
                d = fmaf(We[HIDDEN + j], b2[j], d);
            }
            w2c[0] = s;
            w2c[1] = d;
        }
        return;
    }
    __shared__ int sums[256];
    int v0 = b * 1024 + t * 4;
    bool ok = v0 < N_NODES;
    unsigned si0 = 0, si1 = 0, si2 = 0, si3 = 0;
    unsigned so0 = 0, so1 = 0, so2 = 0, so3 = 0;
    if (ok) {
        int w0 = v0 >> 1;  // even (v0 % 4 == 0) -> uint2 aligned
#pragma unroll
        for (int c = 0; c < CSPLIT; ++c) {
            uint2 a = *reinterpret_cast<const uint2*>(pin + (size_t)c * (N_NODES / 2) + w0);
            uint2 o = *reinterpret_cast<const uint2*>(pout + (size_t)c * (N_NODES / 2) + w0);
            si0 += a.x & 0xffffu; si1 += a.x >> 16;
            si2 += a.y & 0xffffu; si3 += a.y >> 16;
            so0 += o.x & 0xffffu; so1 += o.x >> 16;
            so2 += o.y & 0xffffu; so3 += o.y >> 16;
        }
        *reinterpret_cast<float4*>(cs + v0) =
            make_float4(rsqrtf(fmaxf((float)so0, 1.f)), rsqrtf(fmaxf((float)so1, 1.f)),
                        rsqrtf(fmaxf((float)so2, 1.f)), rsqrtf(fmaxf((float)so3, 1.f)));
        *reinterpret_cast<float4*>(cd + v0) =
            make_float4(rsqrtf(fmaxf((float)si0, 1.f)), rsqrtf(fmaxf((float)si1, 1.f)),
                        rsqrtf(fmaxf((float)si2, 1.f)), rsqrtf(fmaxf((float)si3, 1.f)));
    }
    int d0 = (int)si0, d1 = (int)si1, d2 = (int)si2, d3 = (int)si3;
    sums[t] = d0 + d1 + d2 + d3;
    __syncthreads();
    for (int o = 1; o < 256; o <<= 1) {
        int v = (t >= o) ? sums[t - o] : 0;
        __syncthreads();
        sums[t] += v;
        __syncthreads();
    }
    int excl = (t == 0) ? 0 : sums[t - 1];
    if (ok) {
        *reinterpret_cast<int4*>(offs + v0) =
            make_int4(excl, excl + d0, excl + d0 + d1, excl + d0 + d1 + d2);
    }
    if (t == 255) bsum[b] = sums[255];
}

// --- finalize offs + RELATIVE per-chunk base offsets (u16) ---
__global__ __launch_bounds__(256) void scan3_base_kernel(int* __restrict__ offs,
                                                         const int* __restrict__ bsum,
                                                         const unsigned* __restrict__ pin,
                                                         unsigned short* __restrict__ baser) {
    __shared__ int sbase[64];
    int t = threadIdx.x;
    if (t < 64) {
        int val = (t < 49) ? bsum[t] : 0;
        int s = val;
#pragma unroll
        for (int o = 1; o < 64; o <<= 1) {
            int u = __shfl_up(s, o, 64);
            if (t >= o) s += u;
        }
        sbase[t] = s - val;  // exclusive
    }
    __syncthreads();
    int v = blockIdx.x * 256 + t;
    if (v >= N_NODES) return;
    int off = offs[v] + sbase[v >> 10];
    offs[v] = off;
    int rel = 0;
    int sh = (v & 1) * 16;
#pragma unroll
    for (int c = 0; c < CSPLIT; ++c) {
        baser[(size_t)c * N_NODES + v] = (unsigned short)rel;
        rel += (int)((pin[(size_t)c * (N_NODES / 2) + (v >> 1)] >> sh) & 0xffffu);
    }
    if (v == 0) offs[N_NODES] = N_EDGES;
}

// --- CSR fill: slot = offs[dst] + baser[c][dst] + epos ---
__global__ __launch_bounds__(256) void fill_kernel(const int* __restrict__ src,
                                                   const int* __restrict__ dst,
                                                   const unsigned short* __restrict__ epos,
                                                   const int* __restrict__ offs,
                                                   const unsigned short* __restrict__ baser,
                                                   int* __restrict__ csr_src) {
    int t = blockIdx.x * 256 + threadIdx.x;
    int e0 = t * 4;
    if (e0 >= N_EDGES) return;
    int c = e0 / CHUNK;  // CHUNK % 4 == 0 -> uniform over the 4 edges
    const unsigned short* brc = baser + (size_t)c * N_NODES;
    int4 s = *reinterpret_cast<const int4*>(src + e0);
    int4 d = *reinterpret_cast<const int4*>(dst + e0);
    ushort4 ep = *reinterpret_cast<const ushort4*>(epos + e0);
    csr_src[offs[d.x] + brc[d.x] + ep.x] = s.x;
    csr_src[offs[d.y] + brc[d.y] + ep.y] = s.y;
    csr_src[offs[d.z] + brc[d.z] + ep.z] = s.z;
    csr_src[offs[d.w] + brc[d.w] + ep.w] = s.w;
}

// --- layer1 gather, FOUR node-streams per wave with predicated batch loads
//     (r15 post-mortem: y-table is cache-resident; gather_t is latency-bound
//     -> raise in-flight loads per wave at unchanged instruction count).
//     8 edge-slots x 8 lanes x uint4; stream-active flags are wave-uniform;
//     inactive streams issue clamped (cached) loads killed by cs=0 fma.
//     Per-node accumulation order identical to r14 (same absmax). ---
__global__ __launch_bounds__(256) void gather_t_kernel(const unsigned short* __restrict__ y,
                                                       const int* __restrict__ offs,
                                                       const int* __restrict__ csr_src,
                                                       const float* __restrict__ c_src,
                                                       const float* __restrict__ c_dst,
                                                       const float* __restrict__ b1,
                                                       const float* __restrict__ w2s,
                                                       const float* __restrict__ w2d,
                                                       float2* __restrict__ t) {
    int wid = threadIdx.x >> 6, l = threadIdx.x & 63;
    int slot = l >> 3, q8 = l & 7;       // 8 edge-slots x 8 feature-octets
    int v0 = blockIdx.x * 16 + wid * 4;  // grid exact: 3125 * 16 = 50000
    int4 ob = *reinterpret_cast<const int4*>(offs + v0);
    int E3 = offs[v0 + 4];
    int k0 = ob.x, E0 = ob.y;
    int k1 = ob.y, E1 = ob.z;
    int k2 = ob.z, E2 = ob.w;
    int k3 = ob.w;
    float acc0[8] = {0.f, 0.f, 0.f, 0.f, 0.f, 0.f, 0.f, 0.f};
    float acc1[8] = {0.f, 0.f, 0.f, 0.f, 0.f, 0.f, 0.f, 0.f};
    float acc2[8] = {0.f, 0.f, 0.f, 0.f, 0.f, 0.f, 0.f, 0.f};
    float acc3[8] = {0.f, 0.f, 0.f, 0.f, 0.f, 0.f, 0.f, 0.f};
    for (;;) {
        bool a0 = k0 + 8 <= E0, a1 = k1 + 8 <= E1, a2 = k2 + 8 <= E2, a3 = k3 + 8 <= E3;
        if (!(a0 | a1 | a2 | a3)) break;
        int i0 = min(k0 + slot, N_EDGES - 1);
        int i1 = min(k1 + slot, N_EDGES - 1);
        int i2 = min(k2 + slot, N_EDGES - 1);
        int i3 = min(k3 + slot, N_EDGES - 1);
        int s0 = csr_src[i0];
        int s1 = csr_src[i1];
        int s2 = csr_src[i2];
        int s3 = csr_src[i3];
        float cs0 = a0 ? c_src[s0] : 0.f;
        float cs1 = a1 ? c_src[s1] : 0.f;
        float cs2 = a2 ? c_src[s2] : 0.f;
        float cs3 = a3 ? c_src[s3] : 0.f;
        uint4 r0 = *reinterpret_cast<const uint4*>(y + (size_t)s0 * HIDDEN + q8 * 8);
        uint4 r1 = *reinterpret_cast<const uint4*>(y + (size_t)s1 * HIDDEN + q8 * 8);
        uint4 r2 = *reinterpret_cast<const uint4*>(y + (size_t)s2 * HIDDEN + q8 * 8);
        uint4 r3 = *reinterpret_cast<const uint4*>(y + (size_t)s3 * HIDDEN + q8 * 8);
        ACC8F(acc0, r0, cs0);
        ACC8F(acc1, r1, cs1);
        ACC8F(acc2, r2, cs2);
        ACC8F(acc3, r3, cs3);
        if (a0) k0 += 8;
        if (a1) k1 += 8;
        if (a2) k2 += 8;
        if (a3) k3 += 8;
    }
    // tails (<8 edges each)
    if (slot < E0 - k0) {
        int s = csr_src[k0 + slot];
        float cs = c_src[s];
        uint4 r = *reinterpret_cast<const uint4*>(y + (size_t)s * HIDDEN + q8 * 8);
        ACC8F(acc0, r, cs);
    }
    if (slot < E1 - k1) {
        int s = csr_src[k1 + slot];
        float cs = c_src[s];
        uint4 r = *reinterpret_cast<const uint4*>(y + (size_t)s * HIDDEN + q8 * 8);
        ACC8F(acc1, r, cs);
    }
    if (slot < E2 - k2) {
        int s = csr_src[k2 + slot];
        float cs = c_src[s];
        uint4 r = *reinterpret_cast<const uint4*>(y + (size_t)s * HIDDEN + q8 * 8);
        ACC8F(acc2, r, cs);
    }
    if (slot < E3 - k3) {
        int s = csr_src[k3 + slot];
        float cs = c_src[s];
        uint4 r = *reinterpret_cast<const uint4*>(y + (size_t)s * HIDDEN + q8 * 8);
        ACC8F(acc3, r, cs);
    }
    // combine 8 slots (lanes with equal q8), all four nodes
#pragma unroll
    for (int i = 0; i < 8; ++i) {
        acc0[i] += __shfl_xor(acc0[i], 8, 64);
        acc0[i] += __shfl_xor(acc0[i], 16, 64);
        acc0[i] += __shfl_xor(acc0[i], 32, 64);
        acc1[i] += __shfl_xor(acc1[i], 8, 64);
        acc1[i] += __shfl_xor(acc1[i], 16, 64);
        acc1[i] += __shfl_xor(acc1[i], 32, 64);
        acc2[i] += __shfl_xor(acc2[i], 8, 64);
        acc2[i] += __shfl_xor(acc2[i], 16, 64);
        acc2[i] += __shfl_xor(acc2[i], 32, 64);
        acc3[i] += __shfl_xor(acc3[i], 8, 64);
        acc3[i] += __shfl_xor(acc3[i], 16, 64);
        acc3[i] += __shfl_xor(acc3[i], 32, 64);
    }
    float4 ba = *reinterpret_cast<const float4*>(b1 + q8 * 8);
    float4 bb = *reinterpret_cast<const float4*>(b1 + q8 * 8 + 4);
    float4 wsa = *reinterpret_cast<const float4*>(w2s + q8 * 8);
    float4 wsb = *reinterpret_cast<const float4*>(w2s + q8 * 8 + 4);
    float4 wda = *reinterpret_cast<const float4*>(w2d + q8 * 8);
    float4 wdb = *reinterpret_cast<const float4*>(w2d + q8 * 8 + 4);
    float4 cdv = *reinterpret_cast<const float4*>(c_dst + v0);
    float4 csv = *reinterpret_cast<const float4*>(c_src + v0);
    float ps[4], pd[4];
    const float* cdp = &cdv.x;
    float* accs[4] = {acc0, acc1, acc2, acc3};
#pragma unroll
    for (int j = 0; j < 4; ++j) {
        float c = cdp[j];
        float* A = accs[j];
        float h0 = fmaxf(fmaf(c, A[0], ba.x), 0.f);
        float h1 = fmaxf(fmaf(c, A[1], ba.y), 0.f);
        float h2 = fmaxf(fmaf(c, A[2], ba.z), 0.f);
        float h3 = fmaxf(fmaf(c, A[3], ba.w), 0.f);
        float h4 = fmaxf(fmaf(c, A[4], bb.x), 0.f);
        float h5 = fmaxf(fmaf(c, A[5], bb.y), 0.f);
        float h6 = fmaxf(fmaf(c, A[6], bb.z), 0.f);
        float h7 = fmaxf(fmaf(c, A[7], bb.w), 0.f);
        ps[j] = h0 * wsa.x + h1 * wsa.y + h2 * wsa.z + h3 * wsa.w
              + h4 * wsb.x + h5 * wsb.y + h6 * wsb.z + h7 * wsb.w;
        pd[j] = h0 * wda.x + h1 * wda.y + h2 * wda.z + h3 * wda.w
              + h4 * wdb.x + h5 * wdb.y + h6 * wdb.z + h7 * wdb.w;
    }
#pragma unroll
    for (int o = 1; o <= 4; o <<= 1) {
#pragma unroll
        for (int j = 0; j < 4; ++j) {
            ps[j] += __shfl_xor(ps[j], o, 64);
            pd[j] += __shfl_xor(pd[j], o, 64);
        }
    }
    if (l == 0) {
        *reinterpret_cast<float4*>(t + v0) =
            make_float4(csv.x * ps[0], csv.x * pd[0], csv.y * ps[1], csv.y * pd[1]);
    } else if (l == 1) {
        *reinterpret_cast<float4*>(t + v0 + 2) =
            make_float4(csv.z * ps[2], csv.z * pd[2], csv.w * ps[3], csv.w * pd[3]);
    }
}

// --- layer2 scalar gather: a_s[v] = c_dst[v]*sum(t_s over in-edges) + Ws.b2 ---
__global__ __launch_bounds__(256) void gather2_kernel(const float2* __restrict__ t,
                                                      const int* __restrict__ offs,
                                                      const int* __restrict__ csr_src,
                                                      const float* __restrict__ c_dst,
                                                      const float* __restrict__ w2c,
                                                      float* __restrict__ a_s,
                                                      float* __restrict__ a_d) {
    int wid = threadIdx.x >> 6, l = threadIdx.x & 63;
    int sub = l >> 4, q = l & 15;
    int v = blockIdx.x * 16 + wid * 4 + sub;  // grid exact: 3125 * 16 = 50000
    int beg = offs[v], end = offs[v + 1];
    float ps = 0.f, pd = 0.f;
    for (int k = beg + q; k < end; k += 16) {
        float2 tv = t[csr_src[k]];
        ps += tv.x;
        pd += tv.y;
    }
#pragma unroll
    for (int o = 1; o <= 8; o <<= 1) {
        ps += __shfl_xor(ps, o, 64);
        pd += __shfl_xor(pd, o, 64);
    }
    if (q == 0) {
        float c = c_dst[v];
        a_s[v] = fmaf(c, ps, w2c[0]);
        a_d[v] = fmaf(c, pd, w2c[1]);
    }
}

// --- out[e] = sigmoid(a_s[src] + a_d[dst] + efeat.Wf + be), 8 edges/thread ---
__global__ __launch_bounds__(256) void edge_out_kernel(const int* __restrict__ src,
                                                       const int* __restrict__ dst,
                                                       const float* __restrict__ efeat,
                                                       const float* __restrict__ We,
                                                       const float* __restrict__ be,
                                                       const float* __restrict__ a_s,
                                                       const float* __restrict__ a_d,
                                                       float* __restrict__ out) {
    int t = blockIdx.x * 256 + threadIdx.x;
    int e0 = t * 8;
    if (e0 >= N_EDGES) return;  // N_EDGES % 8 == 0 -> full octets
    float w0 = We[2 * HIDDEN + 0], w1 = We[2 * HIDDEN + 1], w2 = We[2 * HIDDEN + 2];
    float b = be[0];
    int4 sA = *reinterpret_cast<const int4*>(src + e0);
    int4 sB = *reinterpret_cast<const int4*>(src + e0 + 4);
    int4 dA = *reinterpret_cast<const int4*>(dst + e0);
    int4 dB = *reinterpret_cast<const int4*>(dst + e0 + 4);
    const float4* f = reinterpret_cast<const float4*>(efeat + (long)e0 * 3);
    float4 f0 = f[0], f1 = f[1], f2 = f[2], f3 = f[3], f4 = f[4], f5 = f[5];
    float as0 = a_s[sA.x], as1 = a_s[sA.y], as2 = a_s[sA.z], as3 = a_s[sA.w];
    float as4 = a_s[sB.x], as5 = a_s[sB.y], as6 = a_s[sB.z], as7 = a_s[sB.w];
    float ad0 = a_d[dA.x], ad1 = a_d[dA.y], ad2 = a_d[dA.z], ad3 = a_d[dA.w];
    float ad4 = a_d[dB.x], ad5 = a_d[dB.y], ad6 = a_d[dB.z], ad7 = a_d[dB.w];
    float4 oA, oB;
    float z;
    z = as0 + ad0 + f0.x * w0 + f0.y * w1 + f0.z * w2 + b;
    oA.x = 1.0f / (1.0f + __expf(-z));
    z = as1 + ad1 + f0.w * w0 + f1.x * w1 + f1.y * w2 + b;
    oA.y = 1.0f / (1.0f + __expf(-z));
    z = as2 + ad2 + f1.z * w0 + f1.w * w1 + f2.x * w2 + b;
    oA.z = 1.0f / (1.0f + __expf(-z));
    z = as3 + ad3 + f2.y * w0 + f2.z * w1 + f2.w * w2 + b;
    oA.w = 1.0f / (1.0f + __expf(-z));
    z = as4 + ad4 + f3.x * w0 + f3.y * w1 + f3.z * w2 + b;
    oB.x = 1.0f / (1.0f + __expf(-z));
    z = as5 + ad5 + f3.w * w0 + f4.x * w1 + f4.y * w2 + b;
    oB.y = 1.0f / (1.0f + __expf(-z));
    z = as6 + ad6 + f4.z * w0 + f4.w * w1 + f5.x * w2 + b;
    oB.z = 1.0f / (1.0f + __expf(-z));
    z = as7 + ad7 + f5.y * w0 + f5.z * w1 + f5.w * w2 + b;
    oB.w = 1.0f / (1.0f + __expf(-z));
    *reinterpret_cast<float4*>(out + e0) = oA;
    *reinterpret_cast<float4*>(out + e0 + 4) = oB;
}

extern "C" void kernel_launch(void* const* d_in, const int* in_sizes, int n_in,
                              void* d_out, int out_size, void* d_ws, size_t ws_size,
                              hipStream_t stream) {
    const float* x     = (const float*)d_in[0];
    const float* efeat = (const float*)d_in[1];
    const int*   src   = (const int*)d_in[2];
    const int*   dst   = (const int*)d_in[3];
    const float* W1    = (const float*)d_in[4];
    const float* b1    = (const float*)d_in[5];
    const float* W2    = (const float*)d_in[6];
    const float* b2    = (const float*)d_in[7];
    const float* We    = (const float*)d_in[8];
    const float* be    = (const float*)d_in[9];
    float* out = (float*)d_out;

    // 256B-aligned workspace carve-up; ~22 MB total.
    char* p = (char*)d_ws;
    auto alloc = [&](size_t bytes) {
        char* r = p;
        p += (bytes + 255) & ~(size_t)255;
        return r;
    };
    float* c_src   = (float*)alloc((size_t)N_NODES * 4);
    float* c_dst   = (float*)alloc((size_t)N_NODES * 4);
    float* a_s     = (float*)alloc((size_t)N_NODES * 4);
    float* a_d     = (float*)alloc((size_t)N_NODES * 4);
    int*   offs    = (int*)alloc((size_t)(N_NODES + 1) * 4);
    int*   bsum    = (int*)alloc(64 * 4);
    float* w2s     = (float*)alloc(HIDDEN * 4);
    float* w2d     = (float*)alloc(HIDDEN * 4);
    float* w2c     = (float*)alloc(2 * 4);
    unsigned*       pin   = (unsigned*)alloc((size_t)CSPLIT * (N_NODES / 2) * 4);  // 3.2 MB
    unsigned*       pout  = (unsigned*)alloc((size_t)CSPLIT * (N_NODES / 2) * 4);  // 3.2 MB
    unsigned short* epos  = (unsigned short*)alloc((size_t)N_EDGES * 2);           // 1.6 MB
    unsigned short* baser = (unsigned short*)alloc((size_t)CSPLIT * N_NODES * 2);  // 3.2 MB
    int*            csr_src = (int*)alloc((size_t)N_EDGES * 4);                    // 3.2 MB
    unsigned short* yb    = (unsigned short*)alloc((size_t)N_NODES * HIDDEN * 2);  // 6.4 MB
    float2*         t     = (float2*)alloc((size_t)N_NODES * 8);                   // 400 KB

    const int NB_V = (N_NODES + 255) / 256;  // 196

    // launch 1: histograms (LDS atomics) overlapped with dep-free MFMA GEMM
    hist_gemm_kernel<<<NB_HIST + NB_GEMM, 256, 0, stream>>>(src, dst, epos, pin, pout,
                                                            x, W1, yb);
    // degree/scan/w2 prep ; offs + relative base finalize
    prep_kernel<<<50, 256, 0, stream>>>(pin, pout, c_src, c_dst, offs, bsum,
                                        W2, We, b2, w2s, w2d, w2c);
    scan3_base_kernel<<<NB_V, 256, 0, stream>>>(offs, bsum, pin, baser);
    // CSR fill
    fill_kernel<<<NB_E4, 256, 0, stream>>>(src, dst, epos, offs, baser, csr_src);
    // fused gather1 + relu + layer-2 dots -> t (4 node-streams/wave)
    gather_t_kernel<<<N_NODES / 16, 256, 0, stream>>>(yb, offs, csr_src, c_src, c_dst,
                                                      b1, w2s, w2d, t);
    // layer-2 scalar gather -> a_s, a_d
    gather2_kernel<<<N_NODES / 16, 256, 0, stream>>>(t, offs, csr_src, c_dst, w2c, a_s, a_d);
    // edge output
    edge_out_kernel<<<(N_EDGES / 8 + 255) / 256, 256, 0, stream>>>(src, dst, efeat, We, be,
                                                                   a_s, a_d, out);
}

// Round 17
// 93.434 us; speedup vs baseline: 1.2097x; 1.0604x over previous
//
#include <hip/hip_runtime.h>
#include <math.h>
#include <stdint.h>

#define N_NODES 50000
#define N_EDGES 800000
#define IN_FEATS 128
#define HIDDEN 64

// CSR build: 32 edge-chunks x (in|out) x 4 node-quarters, counts in LDS (packed
// 2 nodes per u32). The in-histogram pass ALSO emits each edge's slot index
// (epos, u16) so the CSR fill is a single coalesced pass. Zero global atomics
// (r6 post-mortem: device atomics write ~32B through to HBM each; spreading
// them doesn't help -- only reducing their count to zero does).
#define CSPLIT 32
#define CHUNK (N_EDGES / CSPLIT)   // 25000 edges, exact
#define NQUART (N_NODES / 4)       // 12500 nodes per quarter
#define NQWORDS (NQUART / 2)       // 6250 packed u32 (25 KB LDS)

#define NB_HIST 256                // 32 chunks x 2 kinds x 4 quarters
#define NB_E4 782                  // ceil(200000/256) edge-quad blocks
#define NB_GEMM 782                // ceil(50000/64) 64-row MFMA tiles

typedef __attribute__((ext_vector_type(8))) short bf16x8;
typedef __attribute__((ext_vector_type(4))) float f32x4;

__device__ __forceinline__ unsigned short f2bf(float f) {
    unsigned u = __float_as_uint(f);
    u = (u + 0x7FFF + ((u >> 16) & 1)) >> 16;  // RNE
    return (unsigned short)u;
}

// scaled accumulate of a bf16x8 row (uint4) with per-edge c_src factor
#define ACC8F(A, r, cs)                                        \
    A[0] = fmaf(cs, __uint_as_float((r).x << 16), A[0]);       \
    A[1] = fmaf(cs, __uint_as_float((r).x & 0xffff0000u), A[1]); \
    A[2] = fmaf(cs, __uint_as_float((r).y << 16), A[2]);       \
    A[3] = fmaf(cs, __uint_as_float((r).y & 0xffff0000u), A[3]); \
    A[4] = fmaf(cs, __uint_as_float((r).z << 16), A[4]);       \
    A[5] = fmaf(cs, __uint_as_float((r).z & 0xffff0000u), A[5]); \
    A[6] = fmaf(cs, __uint_as_float((r).w << 16), A[6]);       \
    A[7] = fmaf(cs, __uint_as_float((r).w & 0xffff0000u), A[7]);

// --- FUSED launch 1: blocks [0, NB_HIST) = histograms (LDS atomics) ;
//     blocks [NB_HIST, +NB_GEMM) = MFMA GEMM yb = bf16(x @ W1), UNSCALED
//     (c_src applied at gather time -- gemm has no deps, hides under hist). ---
__global__ __launch_bounds__(256) void hist_gemm_kernel(const int* __restrict__ src,
                                                        const int* __restrict__ dst,
                                                        unsigned short* __restrict__ epos,
                                                        unsigned* __restrict__ pin,
                                                        unsigned* __restrict__ pout,
                                                        const float* __restrict__ x,
                                                        const float* __restrict__ W,
                                                        unsigned short* __restrict__ yb) {
    __shared__ union {
        unsigned cnt[NQWORDS];   // 25 KB (hist blocks)
        bf16x8 bfrag[16][64];    // 16 KB (gemm blocks)
    } u;
    if (blockIdx.x < NB_HIST) {
        int b = blockIdx.x;
        int c = b >> 3;
        int kind = (b >> 2) & 1;   // 0 = in (dst) + epos, 1 = out (src)
        int quar = b & 3;
        int lo = quar * NQUART;
        for (int i = threadIdx.x; i < NQWORDS; i += 256) u.cnt[i] = 0;
        __syncthreads();
        if (kind == 0) {
            const int4* d4 = reinterpret_cast<const int4*>(dst + c * CHUNK);
            for (int i = threadIdx.x; i < CHUNK / 4; i += 256) {
                int4 d = d4[i];
                int e = c * CHUNK + i * 4;
                unsigned q, old;
                q = (unsigned)(d.x - lo);
                if (q < NQUART) { old = atomicAdd(&u.cnt[q >> 1], 1u << ((q & 1) * 16));
                                  epos[e + 0] = (unsigned short)(old >> ((q & 1) * 16)); }
                q = (unsigned)(d.y - lo);
                if (q < NQUART) { old = atomicAdd(&u.cnt[q >> 1], 1u << ((q & 1) * 16));
                                  epos[e + 1] = (unsigned short)(old >> ((q & 1) * 16)); }
                q = (unsigned)(d.z - lo);
                if (q < NQUART) { old = atomicAdd(&u.cnt[q >> 1], 1u << ((q & 1) * 16));
                                  epos[e + 2] = (unsigned short)(old >> ((q & 1) * 16)); }
                q = (unsigned)(d.w - lo);
                if (q < NQUART) { old = atomicAdd(&u.cnt[q >> 1], 1u << ((q & 1) * 16));
                                  epos[e + 3] = (unsigned short)(old >> ((q & 1) * 16)); }
            }
        } else {
            const int4* s4 = reinterpret_cast<const int4*>(src + c * CHUNK);
            for (int i = threadIdx.x; i < CHUNK / 4; i += 256) {
                int4 s = s4[i];
                unsigned q;
                q = (unsigned)(s.x - lo); if (q < NQUART) atomicAdd(&u.cnt[q >> 1], 1u << ((q & 1) * 16));
                q = (unsigned)(s.y - lo); if (q < NQUART) atomicAdd(&u.cnt[q >> 1], 1u << ((q & 1) * 16));
                q = (unsigned)(s.z - lo); if (q < NQUART) atomicAdd(&u.cnt[q >> 1], 1u << ((q & 1) * 16));
                q = (unsigned)(s.w - lo); if (q < NQUART) atomicAdd(&u.cnt[q >> 1], 1u << ((q & 1) * 16));
            }
        }
        __syncthreads();
        unsigned* outp = (kind ? pout : pin) + c * (N_NODES / 2) + quar * NQWORDS;
        for (int i = threadIdx.x; i < NQWORDS; i += 256) outp[i] = u.cnt[i];
        return;
    }
    // ---- MFMA GEMM: yb = bf16(x @ W1), unscaled ----
    // C layout (m89): col = lane&15, row = (lane>>4)*4 + reg.
    int gb = blockIdx.x - NB_HIST;
    for (int idx = threadIdx.x; idx < 16 * 64; idx += 256) {
        int f = idx >> 6, l = idx & 63;
        int nt = f >> 2, kt = f & 3;
        int col = nt * 16 + (l & 15);
        int k0 = kt * 32 + (l >> 4) * 8;
        bf16x8 bv;
#pragma unroll
        for (int j = 0; j < 8; ++j) bv[j] = (short)f2bf(W[(k0 + j) * HIDDEN + col]);
        u.bfrag[f][l] = bv;
    }
    __syncthreads();
    int wid = threadIdx.x >> 6, l = threadIdx.x & 63;
    bf16x8 Breg[16];
#pragma unroll
    for (int f = 0; f < 16; ++f) Breg[f] = u.bfrag[f][l];

    int row0 = gb * 64 + wid * 16;  // this wave's 16-row tile
    int arow = row0 + (l & 15);
    int asafe = min(arow, N_NODES - 1);  // clamp OOB rows (stores guarded)
    const float* xr = x + (size_t)asafe * IN_FEATS + (l >> 4) * 8;
    f32x4 acc0 = {0.f, 0.f, 0.f, 0.f};
    f32x4 acc1 = {0.f, 0.f, 0.f, 0.f};
    f32x4 acc2 = {0.f, 0.f, 0.f, 0.f};
    f32x4 acc3 = {0.f, 0.f, 0.f, 0.f};
#pragma unroll
    for (int kt = 0; kt < 4; ++kt) {
        float4 a0 = *reinterpret_cast<const float4*>(xr + kt * 32);
        float4 a1 = *reinterpret_cast<const float4*>(xr + kt * 32 + 4);
        bf16x8 av;
        av[0] = (short)f2bf(a0.x); av[1] = (short)f2bf(a0.y);
        av[2] = (short)f2bf(a0.z); av[3] = (short)f2bf(a0.w);
        av[4] = (short)f2bf(a1.x); av[5] = (short)f2bf(a1.y);
        av[6] = (short)f2bf(a1.z); av[7] = (short)f2bf(a1.w);
        acc0 = __builtin_amdgcn_mfma_f32_16x16x32_bf16(av, Breg[0 * 4 + kt], acc0, 0, 0, 0);
        acc1 = __builtin_amdgcn_mfma_f32_16x16x32_bf16(av, Breg[1 * 4 + kt], acc1, 0, 0, 0);
        acc2 = __builtin_amdgcn_mfma_f32_16x16x32_bf16(av, Breg[2 * 4 + kt], acc2, 0, 0, 0);
        acc3 = __builtin_amdgcn_mfma_f32_16x16x32_bf16(av, Breg[3 * 4 + kt], acc3, 0, 0, 0);
    }
#pragma unroll
    for (int i = 0; i < 4; ++i) {
        int row = row0 + (l >> 4) * 4 + i;
        if (row < N_NODES) {
            unsigned short* yr = yb + (size_t)row * HIDDEN + (l & 15);
            yr[0]  = f2bf(acc0[i]);
            yr[16] = f2bf(acc1[i]);
            yr[32] = f2bf(acc2[i]);
            yr[48] = f2bf(acc3[i]);
        }
    }
}

// --- fused: degree-sum + c_src/c_dst + per-block exclusive scan (blocks 0..48,
//     1024 nodes each, 4/thread) ; block 49 = w2prep (w2s=W2@Ws, w2d=W2@Wd) ---
__global__ __launch_bounds__(256) void prep_kernel(const unsigned* __restrict__ pin,
                                                   const unsigned* __restrict__ pout,
                                                   float* __restrict__ cs,
                                                   float* __restrict__ cd,
                                                   int* __restrict__ offs,
                                                   int* __restrict__ bsum,
                                                   const float* __restrict__ W2,
                                                   const float* __restrict__ We,
                                                   const float* __restrict__ b2,
                                                   float* __restrict__ w2s,
                                                   float* __restrict__ w2d,
                                                   float* __restrict__ w2c) {
    int b = blockIdx.x;
    int t = threadIdx.x;
    if (b == 49) {  // w2prep tail block (no barriers on this path)
        if (t < 64) {
            float s = 0.f, d = 0.f;
            for (int j = 0; j < HIDDEN; ++j) {
                float w = W2[t * HIDDEN + j];
                s = fmaf(w, We[j], s);
                d = fmaf(w, We[HIDDEN + j], d);
            }
            w2s[t] = s;
            w2d[t] = d;
        } else if (t == 64) {
            float s = 0.f, d = 0.f;
            for (int j = 0; j < HIDDEN; ++j) {
                s = fmaf(We[j], b2[j], s);
                d = fmaf(We[HIDDEN + j], b2[j], d);
            }
            w2c[0] = s;
            w2c[1] = d;
        }
        return;
    }
    __shared__ int sums[256];
    int v0 = b * 1024 + t * 4;
    bool ok = v0 < N_NODES;
    unsigned si0 = 0, si1 = 0, si2 = 0, si3 = 0;
    unsigned so0 = 0, so1 = 0, so2 = 0, so3 = 0;
    if (ok) {
        int w0 = v0 >> 1;  // even (v0 % 4 == 0) -> uint2 aligned
#pragma unroll
        for (int c = 0; c < CSPLIT; ++c) {
            uint2 a = *reinterpret_cast<const uint2*>(pin + (size_t)c * (N_NODES / 2) + w0);
            uint2 o = *reinterpret_cast<const uint2*>(pout + (size_t)c * (N_NODES / 2) + w0);
            si0 += a.x & 0xffffu; si1 += a.x >> 16;
            si2 += a.y & 0xffffu; si3 += a.y >> 16;
            so0 += o.x & 0xffffu; so1 += o.x >> 16;
            so2 += o.y & 0xffffu; so3 += o.y >> 16;
        }
        *reinterpret_cast<float4*>(cs + v0) =
            make_float4(rsqrtf(fmaxf((float)so0, 1.f)), rsqrtf(fmaxf((float)so1, 1.f)),
                        rsqrtf(fmaxf((float)so2, 1.f)), rsqrtf(fmaxf((float)so3, 1.f)));
        *reinterpret_cast<float4*>(cd + v0) =
            make_float4(rsqrtf(fmaxf((float)si0, 1.f)), rsqrtf(fmaxf((float)si1, 1.f)),
                        rsqrtf(fmaxf((float)si2, 1.f)), rsqrtf(fmaxf((float)si3, 1.f)));
    }
    int d0 = (int)si0, d1 = (int)si1, d2 = (int)si2, d3 = (int)si3;
    sums[t] = d0 + d1 + d2 + d3;
    __syncthreads();
    for (int o = 1; o < 256; o <<= 1) {
        int v = (t >= o) ? sums[t - o] : 0;
        __syncthreads();
        sums[t] += v;
        __syncthreads();
    }
    int excl = (t == 0) ? 0 : sums[t - 1];
    if (ok) {
        *reinterpret_cast<int4*>(offs + v0) =
            make_int4(excl, excl + d0, excl + d0 + d1, excl + d0 + d1 + d2);
    }
    if (t == 255) bsum[b] = sums[255];
}

// --- finalize offs + RELATIVE per-chunk base offsets (u16) ---
__global__ __launch_bounds__(256) void scan3_base_kernel(int* __restrict__ offs,
                                                         const int* __restrict__ bsum,
                                                         const unsigned* __restrict__ pin,
                                                         unsigned short* __restrict__ baser) {
    __shared__ int sbase[64];
    int t = threadIdx.x;
    if (t < 64) {
        int val = (t < 49) ? bsum[t] : 0;
        int s = val;
#pragma unroll
        for (int o = 1; o < 64; o <<= 1) {
            int u = __shfl_up(s, o, 64);
            if (t >= o) s += u;
        }
        sbase[t] = s - val;  // exclusive
    }
    __syncthreads();
    int v = blockIdx.x * 256 + t;
    if (v >= N_NODES) return;
    int off = offs[v] + sbase[v >> 10];
    offs[v] = off;
    int rel = 0;
    int sh = (v & 1) * 16;
#pragma unroll
    for (int c = 0; c < CSPLIT; ++c) {
        baser[(size_t)c * N_NODES + v] = (unsigned short)rel;
        rel += (int)((pin[(size_t)c * (N_NODES / 2) + (v >> 1)] >> sh) & 0xffffu);
    }
    if (v == 0) offs[N_NODES] = N_EDGES;
}

// --- CSR fill: slot = offs[dst] + baser[c][dst] + epos ---
__global__ __launch_bounds__(256) void fill_kernel(const int* __restrict__ src,
                                                   const int* __restrict__ dst,
                                                   const unsigned short* __restrict__ epos,
                                                   const int* __restrict__ offs,
                                                   const unsigned short* __restrict__ baser,
                                                   int* __restrict__ csr_src) {
    int t = blockIdx.x * 256 + threadIdx.x;
    int e0 = t * 4;
    if (e0 >= N_EDGES) return;
    int c = e0 / CHUNK;  // CHUNK % 4 == 0 -> uniform over the 4 edges
    const unsigned short* brc = baser + (size_t)c * N_NODES;
    int4 s = *reinterpret_cast<const int4*>(src + e0);
    int4 d = *reinterpret_cast<const int4*>(dst + e0);
    ushort4 ep = *reinterpret_cast<const ushort4*>(epos + e0);
    csr_src[offs[d.x] + brc[d.x] + ep.x] = s.x;
    csr_src[offs[d.y] + brc[d.y] + ep.y] = s.y;
    csr_src[offs[d.z] + brc[d.z] + ep.z] = s.z;
    csr_src[offs[d.w] + brc[d.w] + ep.w] = s.w;
}

// --- layer1 gather, TWO nodes per wave interleaved; y rows are UNSCALED, the
//     c_src[src] factor is applied per-edge via fmaf (200 KB table, L2-hot).
//     8 slots x 8 lanes x uint4; relu/bias + layer-2 collapse -> t[v0], t[v1] ---
__global__ __launch_bounds__(256) void gather_t_kernel(const unsigned short* __restrict__ y,
                                                       const int* __restrict__ offs,
                                                       const int* __restrict__ csr_src,
                                                       const float* __restrict__ c_src,
                                                       const float* __restrict__ c_dst,
                                                       const float* __restrict__ b1,
                                                       const float* __restrict__ w2s,
                                                       const float* __restrict__ w2d,
                                                       float2* __restrict__ t) {
    int wid = threadIdx.x >> 6, l = threadIdx.x & 63;
    int slot = l >> 3, q8 = l & 7;      // 8 edge-slots x 8 feature-octets
    int v0 = blockIdx.x * 8 + wid * 2;  // grid exact: 6250 * 8 = 50000
    int v1 = v0 + 1;
    int beg0 = offs[v0], end0 = offs[v0 + 1], end1 = offs[v0 + 2];
    int k0 = beg0, k1 = end0;  // v1's edges start where v0's end
    float acc0[8] = {0.f, 0.f, 0.f, 0.f, 0.f, 0.f, 0.f, 0.f};
    float acc1[8] = {0.f, 0.f, 0.f, 0.f, 0.f, 0.f, 0.f, 0.f};
    // dual main loop: 2 independent gather streams in flight
    while (k0 + 8 <= end0 && k1 + 8 <= end1) {
        int sA = csr_src[k0 + slot];
        int sB = csr_src[k1 + slot];
        float csA = c_src[sA];
        float csB = c_src[sB];
        uint4 rA = *reinterpret_cast<const uint4*>(y + (size_t)sA * HIDDEN + q8 * 8);
        uint4 rB = *reinterpret_cast<const uint4*>(y + (size_t)sB * HIDDEN + q8 * 8);
        ACC8F(acc0, rA, csA);
        ACC8F(acc1, rB, csB);
        k0 += 8;
        k1 += 8;
    }
    while (k0 + 8 <= end0) {
        int s = csr_src[k0 + slot];
        float cs = c_src[s];
        uint4 r = *reinterpret_cast<const uint4*>(y + (size_t)s * HIDDEN + q8 * 8);
        ACC8F(acc0, r, cs);
        k0 += 8;
    }
    while (k1 + 8 <= end1) {
        int s = csr_src[k1 + slot];
        float cs = c_src[s];
        uint4 r = *reinterpret_cast<const uint4*>(y + (size_t)s * HIDDEN + q8 * 8);
        ACC8F(acc1, r, cs);
        k1 += 8;
    }
    if (slot < end0 - k0) {
        int s = csr_src[k0 + slot];
        float cs = c_src[s];
        uint4 r = *reinterpret_cast<const uint4*>(y + (size_t)s * HIDDEN + q8 * 8);
        ACC8F(acc0, r, cs);
    }
    if (slot < end1 - k1) {
        int s = csr_src[k1 + slot];
        float cs = c_src[s];
        uint4 r = *reinterpret_cast<const uint4*>(y + (size_t)s * HIDDEN + q8 * 8);
        ACC8F(acc1, r, cs);
    }
    // combine 8 slots (lanes with equal q8), both nodes
#pragma unroll
    for (int i = 0; i < 8; ++i) {
        acc0[i] += __shfl_xor(acc0[i], 8, 64);
        acc0[i] += __shfl_xor(acc0[i], 16, 64);
        acc0[i] += __shfl_xor(acc0[i], 32, 64);
        acc1[i] += __shfl_xor(acc1[i], 8, 64);
        acc1[i] += __shfl_xor(acc1[i], 16, 64);
        acc1[i] += __shfl_xor(acc1[i], 32, 64);
    }
    float4 ba = *reinterpret_cast<const float4*>(b1 + q8 * 8);
    float4 bb = *reinterpret_cast<const float4*>(b1 + q8 * 8 + 4);
    float4 wsa = *reinterpret_cast<const float4*>(w2s + q8 * 8);
    float4 wsb = *reinterpret_cast<const float4*>(w2s + q8 * 8 + 4);
    float4 wda = *reinterpret_cast<const float4*>(w2d + q8 * 8);
    float4 wdb = *reinterpret_cast<const float4*>(w2d + q8 * 8 + 4);
    float c0 = c_dst[v0], c1 = c_dst[v1];
    float h0, h1, h2, h3, h4, h5, h6, h7;
    h0 = fmaxf(fmaf(c0, acc0[0], ba.x), 0.f);
    h1 = fmaxf(fmaf(c0, acc0[1], ba.y), 0.f);
    h2 = fmaxf(fmaf(c0, acc0[2], ba.z), 0.f);
    h3 = fmaxf(fmaf(c0, acc0[3], ba.w), 0.f);
    h4 = fmaxf(fmaf(c0, acc0[4], bb.x), 0.f);
    h5 = fmaxf(fmaf(c0, acc0[5], bb.y), 0.f);
    h6 = fmaxf(fmaf(c0, acc0[6], bb.z), 0.f);
    h7 = fmaxf(fmaf(c0, acc0[7], bb.w), 0.f);
    float ps0 = h0 * wsa.x + h1 * wsa.y + h2 * wsa.z + h3 * wsa.w
              + h4 * wsb.x + h5 * wsb.y + h6 * wsb.z + h7 * wsb.w;
    float pd0 = h0 * wda.x + h1 * wda.y + h2 * wda.z + h3 * wda.w
              + h4 * wdb.x + h5 * wdb.y + h6 * wdb.z + h7 * wdb.w;
    h0 = fmaxf(fmaf(c1, acc1[0], ba.x), 0.f);
    h1 = fmaxf(fmaf(c1, acc1[1], ba.y), 0.f);
    h2 = fmaxf(fmaf(c1, acc1[2], ba.z), 0.f);
    h3 = fmaxf(fmaf(c1, acc1[3], ba.w), 0.f);
    h4 = fmaxf(fmaf(c1, acc1[4], bb.x), 0.f);
    h5 = fmaxf(fmaf(c1, acc1[5], bb.y), 0.f);
    h6 = fmaxf(fmaf(c1, acc1[6], bb.z), 0.f);
    h7 = fmaxf(fmaf(c1, acc1[7], bb.w), 0.f);
    float ps1 = h0 * wsa.x + h1 * wsa.y + h2 * wsa.z + h3 * wsa.w
              + h4 * wsb.x + h5 * wsb.y + h6 * wsb.z + h7 * wsb.w;
    float pd1 = h0 * wda.x + h1 * wda.y + h2 * wda.z + h3 * wda.w
              + h4 * wdb.x + h5 * wdb.y + h6 * wdb.z + h7 * wdb.w;
#pragma unroll
    for (int o = 1; o <= 4; o <<= 1) {
        ps0 += __shfl_xor(ps0, o, 64);
        pd0 += __shfl_xor(pd0, o, 64);
        ps1 += __shfl_xor(ps1, o, 64);
        pd1 += __shfl_xor(pd1, o, 64);
    }
    if (l == 0) {
        float cs0 = c_src[v0], cs1 = c_src[v1];
        // t[v0], t[v1] are consecutive float2 -> one float4 store (v0 even)
        *reinterpret_cast<float4*>(t + v0) =
            make_float4(cs0 * ps0, cs0 * pd0, cs1 * ps1, cs1 * pd1);
    }
}

// --- layer2 scalar gather: a_s[v] = c_dst[v]*sum(t_s over in-edges) + Ws.b2 ---
__global__ __launch_bounds__(256) void gather2_kernel(const float2* __restrict__ t,
                                                      const int* __restrict__ offs,
                                                      const int* __restrict__ csr_src,
                                                      const float* __restrict__ c_dst,
                                                      const float* __restrict__ w2c,
                                                      float* __restrict__ a_s,
                                                      float* __restrict__ a_d) {
    int wid = threadIdx.x >> 6, l = threadIdx.x & 63;
    int sub = l >> 4, q = l & 15;
    int v = blockIdx.x * 16 + wid * 4 + sub;  // grid exact: 3125 * 16 = 50000
    int beg = offs[v], end = offs[v + 1];
    float ps = 0.f, pd = 0.f;
    for (int k = beg + q; k < end; k += 16) {
        float2 tv = t[csr_src[k]];
        ps += tv.x;
        pd += tv.y;
    }
#pragma unroll
    for (int o = 1; o <= 8; o <<= 1) {
        ps += __shfl_xor(ps, o, 64);
        pd += __shfl_xor(pd, o, 64);
    }
    if (q == 0) {
        float c = c_dst[v];
        a_s[v] = fmaf(c, ps, w2c[0]);
        a_d[v] = fmaf(c, pd, w2c[1]);
    }
}

// --- out[e] = sigmoid(a_s[src] + a_d[dst] + efeat.Wf + be), 8 edges/thread ---
__global__ __launch_bounds__(256) void edge_out_kernel(const int* __restrict__ src,
                                                       const int* __restrict__ dst,
                                                       const float* __restrict__ efeat,
                                                       const float* __restrict__ We,
                                                       const float* __restrict__ be,
                                                       const float* __restrict__ a_s,
                                                       const float* __restrict__ a_d,
                                                       float* __restrict__ out) {
    int t = blockIdx.x * 256 + threadIdx.x;
    int e0 = t * 8;
    if (e0 >= N_EDGES) return;  // N_EDGES % 8 == 0 -> full octets
    float w0 = We[2 * HIDDEN + 0], w1 = We[2 * HIDDEN + 1], w2 = We[2 * HIDDEN + 2];
    float b = be[0];
    int4 sA = *reinterpret_cast<const int4*>(src + e0);
    int4 sB = *reinterpret_cast<const int4*>(src + e0 + 4);
    int4 dA = *reinterpret_cast<const int4*>(dst + e0);
    int4 dB = *reinterpret_cast<const int4*>(dst + e0 + 4);
    const float4* f = reinterpret_cast<const float4*>(efeat + (long)e0 * 3);
    float4 f0 = f[0], f1 = f[1], f2 = f[2], f3 = f[3], f4 = f[4], f5 = f[5];
    float as0 = a_s[sA.x], as1 = a_s[sA.y], as2 = a_s[sA.z], as3 = a_s[sA.w];
    float as4 = a_s[sB.x], as5 = a_s[sB.y], as6 = a_s[sB.z], as7 = a_s[sB.w];
    float ad0 = a_d[dA.x], ad1 = a_d[dA.y], ad2 = a_d[dA.z], ad3 = a_d[dA.w];
    float ad4 = a_d[dB.x], ad5 = a_d[dB.y], ad6 = a_d[dB.z], ad7 = a_d[dB.w];
    float4 oA, oB;
    float z;
    z = as0 + ad0 + f0.x * w0 + f0.y * w1 + f0.z * w2 + b;
    oA.x = 1.0f / (1.0f + __expf(-z));
    z = as1 + ad1 + f0.w * w0 + f1.x * w1 + f1.y * w2 + b;
    oA.y = 1.0f / (1.0f + __expf(-z));
    z = as2 + ad2 + f1.z * w0 + f1.w * w1 + f2.x * w2 + b;
    oA.z = 1.0f / (1.0f + __expf(-z));
    z = as3 + ad3 + f2.y * w0 + f2.z * w1 + f2.w * w2 + b;
    oA.w = 1.0f / (1.0f + __expf(-z));
    z = as4 + ad4 + f3.x * w0 + f3.y * w1 + f3.z * w2 + b;
    oB.x = 1.0f / (1.0f + __expf(-z));
    z = as5 + ad5 + f3.w * w0 + f4.x * w1 + f4.y * w2 + b;
    oB.y = 1.0f / (1.0f + __expf(-z));
    z = as6 + ad6 + f4.z * w0 + f4.w * w1 + f5.x * w2 + b;
    oB.z = 1.0f / (1.0f + __expf(-z));
    z = as7 + ad7 + f5.y * w0 + f5.z * w1 + f5.w * w2 + b;
    oB.w = 1.0f / (1.0f + __expf(-z));
    *reinterpret_cast<float4*>(out + e0) = oA;
    *reinterpret_cast<float4*>(out + e0 + 4) = oB;
}

extern "C" void kernel_launch(void* const* d_in, const int* in_sizes, int n_in,
                              void* d_out, int out_size, void* d_ws, size_t ws_size,
                              hipStream_t stream) {
    const float* x     = (const float*)d_in[0];
    const float* efeat = (const float*)d_in[1];
    const int*   src   = (const int*)d_in[2];
    const int*   dst   = (const int*)d_in[3];
    const float* W1    = (const float*)d_in[4];
    const float* b1    = (const float*)d_in[5];
    const float* W2    = (const float*)d_in[6];
    const float* b2    = (const float*)d_in[7];
    const float* We    = (const float*)d_in[8];
    const float* be    = (const float*)d_in[9];
    float* out = (float*)d_out;

    // 256B-aligned workspace carve-up; ~22 MB total.
    char* p = (char*)d_ws;
    auto alloc = [&](size_t bytes) {
        char* r = p;
        p += (bytes + 255) & ~(size_t)255;
        return r;
    };
    float* c_src   = (float*)alloc((size_t)N_NODES * 4);
    float* c_dst   = (float*)alloc((size_t)N_NODES * 4);
    float* a_s     = (float*)alloc((size_t)N_NODES * 4);
    float* a_d     = (float*)alloc((size_t)N_NODES * 4);
    int*   offs    = (int*)alloc((size_t)(N_NODES + 1) * 4);
    int*   bsum    = (int*)alloc(64 * 4);
    float* w2s     = (float*)alloc(HIDDEN * 4);
    float* w2d     = (float*)alloc(HIDDEN * 4);
    float* w2c     = (float*)alloc(2 * 4);
    unsigned*       pin   = (unsigned*)alloc((size_t)CSPLIT * (N_NODES / 2) * 4);  // 3.2 MB
    unsigned*       pout  = (unsigned*)alloc((size_t)CSPLIT * (N_NODES / 2) * 4);  // 3.2 MB
    unsigned short* epos  = (unsigned short*)alloc((size_t)N_EDGES * 2);           // 1.6 MB
    unsigned short* baser = (unsigned short*)alloc((size_t)CSPLIT * N_NODES * 2);  // 3.2 MB
    int*            csr_src = (int*)alloc((size_t)N_EDGES * 4);                    // 3.2 MB
    unsigned short* yb    = (unsigned short*)alloc((size_t)N_NODES * HIDDEN * 2);  // 6.4 MB
    float2*         t     = (float2*)alloc((size_t)N_NODES * 8);                   // 400 KB

    const int NB_V = (N_NODES + 255) / 256;  // 196

    // launch 1: histograms (LDS atomics) overlapped with dep-free MFMA GEMM
    hist_gemm_kernel<<<NB_HIST + NB_GEMM, 256, 0, stream>>>(src, dst, epos, pin, pout,
                                                            x, W1, yb);
    // degree/scan/w2 prep ; offs + relative base finalize
    prep_kernel<<<50, 256, 0, stream>>>(pin, pout, c_src, c_dst, offs, bsum,
                                        W2, We, b2, w2s, w2d, w2c);
    scan3_base_kernel<<<NB_V, 256, 0, stream>>>(offs, bsum, pin, baser);
    // CSR fill
    fill_kernel<<<NB_E4, 256, 0, stream>>>(src, dst, epos, offs, baser, csr_src);
    // fused gather1 + relu + layer-2 dots -> t (2 nodes/wave, c_src at gather)
    gather_t_kernel<<<N_NODES / 8, 256, 0, stream>>>(yb, offs, csr_src, c_src, c_dst,
                                                     b1, w2s, w2d, t);
    // layer-2 scalar gather -> a_s, a_d
    gather2_kernel<<<N_NODES / 16, 256, 0, stream>>>(t, offs, csr_src, c_dst, w2c, a_s, a_d);
    // edge output
    edge_out_kernel<<<(N_EDGES / 8 + 255) / 256, 256, 0, stream>>>(src, dst, efeat, We, be,
                                                                   a_s, a_d, out);
}